// Round 6
// baseline (277.313 us; speedup 1.0000x reference)
//
#include <hip/hip_runtime.h>
#include <hip/hip_bf16.h>

// AttnDecoder: B=2, Lq=Lkv=2048, E=1024, H=16, D=64, scale = 0.125/sqrt(2).
// Pipeline (all bf16 MFMA, fp32 accum):
//   cast3: q,k,v fp32 -> bf16 row-major
//   wtrans: Wq,Wk,Wv -> bf16 W^T; Wo -> permuted W^T folding head-merge
//   gemm2p (z=0..2): 256x256 2-phase dbuf GEMM -> Qh,Kh [bh][l][c], VhT [bh][c][l]
//   attn: m214-style 32x32 swapped-QK^T flash attention -> Oh [bh][l][c]
//   gemmo: 128x128 2-phase dbuf GEMM, Oh (head-merge folded) @ WoT' -> d_out fp32
// 2-phase = catalog-minimum pipeline: stage(next) BEFORE compute(cur), ONE
// __syncthreads (vmcnt0+barrier) per K-tile. No inline-asm waitcnts (m141/m97:
// compiler emits fine-grained lgkmcnt itself; my r3/r4 hand-pipelines were 3x slower).
// Workspace required: 56 MB.
// [resubmission of round-5 source: r5 bench failed on GPU acquisition, 0 data]

typedef __attribute__((ext_vector_type(8))) short short8;    // 8 x bf16 (4 VGPR)
typedef __attribute__((ext_vector_type(4))) float f32x4;     // 16x16 accumulator
typedef __attribute__((ext_vector_type(16))) float f32x16;   // 32x32 accumulator
typedef __hip_bfloat16 bf16;

#define GLD16(g, l) __builtin_amdgcn_global_load_lds( \
    (const __attribute__((address_space(1))) void*)(g), \
    (__attribute__((address_space(3))) void*)(l), 16, 0, 0)

__device__ __forceinline__ f32x4 mfma16(short8 a, short8 b, f32x4 c) {
  return __builtin_amdgcn_mfma_f32_16x16x32_bf16(a, b, c, 0, 0, 0);
}
__device__ __forceinline__ f32x16 mfma32(short8 a, short8 b, f32x16 c) {
  return __builtin_amdgcn_mfma_f32_32x32x16_bf16(a, b, c, 0, 0, 0);
}

union B8 { bf16 h[8]; int4 v; };
union B4 { bf16 h[4]; int2 v; };

#define QK_SCALE_TOT 0.08838834764831845f              /* 0.125 / sqrt(2) */
#define SC2f (QK_SCALE_TOT * 1.4426950408889634f)      /* -> exp2 domain */

__device__ __forceinline__ float fexp2(float x) {
#if __has_builtin(__builtin_amdgcn_exp2f)
  return __builtin_amdgcn_exp2f(x);
#else
  return exp2f(x);
#endif
}

__device__ __forceinline__ int cvtpk(float lo, float hi_) {
  int r;
  asm("v_cvt_pk_bf16_f32 %0, %1, %2" : "=v"(r) : "v"(lo), "v"(hi_));
  return r;
}

#define ZV16 {0.f,0.f,0.f,0.f,0.f,0.f,0.f,0.f,0.f,0.f,0.f,0.f,0.f,0.f,0.f,0.f}

// ---------------- cast q,k,v -> bf16 (vectorized, G13) ----------------
__global__ __launch_bounds__(256) void cast3_kernel(
    const float* __restrict__ q, const float* __restrict__ k,
    const float* __restrict__ v, bf16* __restrict__ out)
{
  const float* src = (blockIdx.y == 0) ? q : (blockIdx.y == 1) ? k : v;
  bf16* dst = out + (size_t)blockIdx.y * (4u << 20);
  size_t i = ((size_t)blockIdx.x * 256 + threadIdx.x) * 8;
  float4 a = *(const float4*)(src + i);
  float4 b = *(const float4*)(src + i + 4);
  B8 u;
  u.h[0] = __float2bfloat16(a.x); u.h[1] = __float2bfloat16(a.y);
  u.h[2] = __float2bfloat16(a.z); u.h[3] = __float2bfloat16(a.w);
  u.h[4] = __float2bfloat16(b.x); u.h[5] = __float2bfloat16(b.y);
  u.h[6] = __float2bfloat16(b.z); u.h[7] = __float2bfloat16(b.w);
  *(int4*)(dst + i) = u.v;
}

// ---------------- weight transpose (+ Wo head-merge permutation) ----------------
__global__ __launch_bounds__(256) void wtrans_kernel(
    const float* __restrict__ Wq, const float* __restrict__ Wk,
    const float* __restrict__ Wv, const float* __restrict__ Wo,
    bf16* __restrict__ dstbase)
{
  __shared__ bf16 ld[64][68];
  const int z = blockIdx.z;
  const float* src = (z == 0) ? Wq : (z == 1) ? Wk : (z == 2) ? Wv : Wo;
  bf16* dst = dstbase + (size_t)z * (1u << 20);
  const int k0 = blockIdx.x * 64, n0 = blockIdx.y * 64;
  const int t = threadIdx.x;
  const bool perm = (z == 3);
#pragma unroll
  for (int it = 0; it < 4; ++it) {
    int kk = it * 16 + (t >> 4);
    int K = k0 + kk;
    int j = perm ? ((K & 63) * 16 + (K >> 6)) : K;
    float4 vv = *(const float4*)(src + (size_t)j * 1024 + n0 + (t & 15) * 4);
    int c = (t & 15) * 4;
    ld[c + 0][kk] = __float2bfloat16(vv.x);
    ld[c + 1][kk] = __float2bfloat16(vv.y);
    ld[c + 2][kk] = __float2bfloat16(vv.z);
    ld[c + 3][kk] = __float2bfloat16(vv.w);
  }
  __syncthreads();
#pragma unroll
  for (int it = 0; it < 2; ++it) {
    int rr = it * 32 + (t >> 3), cc = (t & 7) * 8;
    B8 u;
#pragma unroll
    for (int e = 0; e < 8; ++e) u.h[e] = ld[rr][cc + e];
    *(int4*)(dst + (size_t)(n0 + rr) * 1024 + k0 + cc) = u.v;
  }
}

// ---------------- 256x256 2-phase projection GEMM, BK=64, 8 waves ----------------
// Per K-tile: stage(buf^1, kt+1) -> ds_read+MFMA on buf -> __syncthreads.
// LDS st_16x32 swizzle (byte ^= ((byte>>9)&1)<<5): linear GLD16 dest +
// inverse-swizzled global source + swizzled ds_read (rule #21).
__global__ __launch_bounds__(512, 2) void gemm2p_kernel(
    const bf16* __restrict__ Abase, const bf16* __restrict__ WTbase,
    bf16* __restrict__ Qh, bf16* __restrict__ Kh, bf16* __restrict__ VhT)
{
  __shared__ bf16 lA[2][256 * 64];
  __shared__ bf16 lB[2][256 * 64];
  const int t = threadIdx.x, lane = t & 63, w = t >> 6;
  const int wr = w >> 2, wc = w & 3;                 // 2M x 4N waves
  const int l15 = lane & 15, l16 = lane >> 4;
  const int rswE = ((l15 >> 2) & 1) << 4;            // read-side swizzle (elems)
  // XCD-aware bijective swizzle of the 64 blocks per z
  const int nblk = blockIdx.x + 4 * blockIdx.y;
  const int sblk = (nblk & 7) * 8 + (nblk >> 3);
  const int tN = (sblk & 3) * 256, tM = (sblk >> 2) * 256;
  const int z = blockIdx.z;
  const bf16* A  = Abase  + (size_t)z * (4u << 20);
  const bf16* BT = WTbase + (size_t)z * (1u << 20);

  // staging: thread covers phys bytes o = i*8192 + t*16 (i=0..3) of each 32KB
  // buffer; logical byte = o ^ ((o>>9)&1)<<5 -> source row/col.
  int oo[4];
  size_t aRow[4], bRow[4];
#pragma unroll
  for (int i = 0; i < 4; ++i) {
    int o = i * 8192 + t * 16;
    int lg = o ^ (((o >> 9) & 1) << 5);
    oo[i] = o >> 1;                       // LDS elem offset
    int sr = lg >> 7;                     // source row 0..255
    int sc = (lg & 127) >> 1;             // source col elem
    aRow[i] = (size_t)(tM + sr) * 1024 + sc;
    bRow[i] = (size_t)(tN + sr) * 1024 + sc;
  }

  auto stage = [&](int buf, int kt) {
#pragma unroll
    for (int i = 0; i < 4; ++i)
      GLD16(A + aRow[i] + (size_t)kt * 64, &lA[buf][oo[i]]);
#pragma unroll
    for (int i = 0; i < 4; ++i)
      GLD16(BT + bRow[i] + (size_t)kt * 64, &lB[buf][oo[i]]);
  };

  f32x4 acc[8][4];
#pragma unroll
  for (int m = 0; m < 8; ++m)
#pragma unroll
    for (int n = 0; n < 4; ++n) acc[m][n] = {0.f, 0.f, 0.f, 0.f};

  stage(0, 0);
  __syncthreads();

  for (int kt = 0; kt < 16; ++kt) {
    const int cur = kt & 1;
    if (kt < 15) stage(cur ^ 1, kt + 1);
#pragma unroll
    for (int kk = 0; kk < 2; ++kk) {
      short8 bfr[4], af[8];
#pragma unroll
      for (int n = 0; n < 4; ++n)
        bfr[n] = *(const short8*)&lB[cur]
            [(wc * 64 + n * 16 + l15) * 64 + ((kk * 32 + l16 * 8) ^ rswE)];
#pragma unroll
      for (int m = 0; m < 8; ++m)
        af[m] = *(const short8*)&lA[cur]
            [(wr * 128 + m * 16 + l15) * 64 + ((kk * 32 + l16 * 8) ^ rswE)];
      __builtin_amdgcn_s_setprio(1);
#pragma unroll
      for (int m = 0; m < 8; ++m)
#pragma unroll
        for (int n = 0; n < 4; ++n)
          acc[m][n] = mfma16(af[m], bfr[n], acc[m][n]);
      __builtin_amdgcn_s_setprio(0);
    }
    __syncthreads();
  }

  // epilogue: 16x16 D-frag layout col = lane&15, row = (lane>>4)*4 + j  [m89]
#pragma unroll
  for (int m = 0; m < 8; ++m) {
#pragma unroll
    for (int n = 0; n < 4; ++n) {
      int col = tN + wc * 64 + n * 16 + l15;
      int rbase = tM + wr * 128 + m * 16 + l16 * 4;
      if (z == 2) {
        // VhT[bh][c][l]; 4 consecutive l -> packed 8B store
        int nh = col & 15, c = col >> 4;
        int b = rbase >> 11, l0 = rbase & 2047;
        B4 u;
#pragma unroll
        for (int j = 0; j < 4; ++j) u.h[j] = __float2bfloat16(acc[m][n][j]);
        *(int2*)&VhT[((size_t)(b * 16 + nh) * 64 + c) * 2048 + l0] = u.v;
      } else {
        bf16* dst = z ? Kh : Qh;  // Qh/Kh[bh][l][c]
        int nh = col & 15, c = col >> 4;
#pragma unroll
        for (int j = 0; j < 4; ++j) {
          int row = rbase + j;
          dst[((size_t)((row >> 11) * 16 + nh) * 2048 + (row & 2047)) * 64 + c] =
              __float2bfloat16(acc[m][n][j]);
        }
      }
    }
  }
}

// ---------------- final GEMM: Oh (head-merge folded) @ WoT' -> fp32 out ----------------
// Same 2-phase skeleton at 128x128, 4 waves (2x2), 256 blocks = full CU coverage.
__global__ __launch_bounds__(256) void gemmo_kernel(
    const bf16* __restrict__ Oh, const bf16* __restrict__ WoT,
    float* __restrict__ Cout)
{
  __shared__ bf16 lA[2][128 * 64];
  __shared__ bf16 lB[2][128 * 64];
  const int t = threadIdx.x, lane = t & 63, w = t >> 6;
  const int wr = w >> 1, wc = w & 1;
  const int l15 = lane & 15, l16 = lane >> 4;
  const int rswE = ((l15 >> 2) & 1) << 4;
  // XCD-aware bijective swizzle of 256 blocks
  const int nblk = blockIdx.x + 8 * blockIdx.y;
  const int sblk = (nblk & 7) * 32 + (nblk >> 3);
  const int tN = (sblk & 7) * 128, tM = (sblk >> 3) * 128;

  int oo[4];
  size_t aRow[4], bRow[4];
#pragma unroll
  for (int i = 0; i < 4; ++i) {
    int o = i * 4096 + t * 16;
    int lg = o ^ (((o >> 9) & 1) << 5);
    oo[i] = o >> 1;
    int sr = lg >> 7;                     // 0..127
    int sc = (lg & 127) >> 1;
    int rg = tM + sr;
    // Oh[bh = b*16 + kt][l][c]: K-tile kt == head index (head-merge folded)
    aRow[i] = ((size_t)(rg >> 11) * 16 * 2048 + (rg & 2047)) * 64 + sc;
    bRow[i] = (size_t)(tN + sr) * 1024 + sc;
  }

  auto stage = [&](int buf, int kt) {
#pragma unroll
    for (int i = 0; i < 4; ++i)
      GLD16(Oh + aRow[i] + (size_t)kt * (2048 * 64), &lA[buf][oo[i]]);
#pragma unroll
    for (int i = 0; i < 4; ++i)
      GLD16(WoT + bRow[i] + kt * 64, &lB[buf][oo[i]]);
  };

  f32x4 acc[4][4];
#pragma unroll
  for (int m = 0; m < 4; ++m)
#pragma unroll
    for (int n = 0; n < 4; ++n) acc[m][n] = {0.f, 0.f, 0.f, 0.f};

  stage(0, 0);
  __syncthreads();

  for (int kt = 0; kt < 16; ++kt) {
    const int cur = kt & 1;
    if (kt < 15) stage(cur ^ 1, kt + 1);
#pragma unroll
    for (int kk = 0; kk < 2; ++kk) {
      short8 bfr[4], af[4];
#pragma unroll
      for (int n = 0; n < 4; ++n)
        bfr[n] = *(const short8*)&lB[cur]
            [(wc * 64 + n * 16 + l15) * 64 + ((kk * 32 + l16 * 8) ^ rswE)];
#pragma unroll
      for (int m = 0; m < 4; ++m)
        af[m] = *(const short8*)&lA[cur]
            [(wr * 64 + m * 16 + l15) * 64 + ((kk * 32 + l16 * 8) ^ rswE)];
      __builtin_amdgcn_s_setprio(1);
#pragma unroll
      for (int m = 0; m < 4; ++m)
#pragma unroll
        for (int n = 0; n < 4; ++n)
          acc[m][n] = mfma16(af[m], bfr[n], acc[m][n]);
      __builtin_amdgcn_s_setprio(0);
    }
    __syncthreads();
  }

#pragma unroll
  for (int m = 0; m < 4; ++m)
#pragma unroll
    for (int n = 0; n < 4; ++n) {
      int col = tN + wc * 64 + n * 16 + l15;
      int rbase = tM + wr * 64 + m * 16 + l16 * 4;
#pragma unroll
      for (int j = 0; j < 4; ++j)
        Cout[(size_t)(rbase + j) * 1024 + col] = acc[m][n][j];
    }
}

// ---------------- flash attention, m214 structure (unchanged, validated) ----------------
__global__ __launch_bounds__(256) void attn_kernel(
    const bf16* __restrict__ Qh, const bf16* __restrict__ Kh,
    const bf16* __restrict__ VhT, bf16* __restrict__ Oh)
{
  __shared__ bf16 Kt[2][64 * 64];
  __shared__ bf16 Vt[2][64 * 64];
  const int t = threadIdx.x, lane = t & 63, w = t >> 6;
  const int l31 = lane & 31, hi = lane >> 5;
  const int bh = blockIdx.y;
  const int q0 = blockIdx.x * 128 + w * 32;
  const size_t baseQK = (size_t)bh * (2048 * 64);
  const size_t baseV  = (size_t)bh * (64 * 2048);

  short8 qf[4];
#pragma unroll
  for (int kc = 0; kc < 4; ++kc)
    qf[kc] = *(const short8*)&Qh[baseQK + (size_t)(q0 + l31) * 64 + kc * 16 + hi * 8];

  const int r0 = t >> 3, g0 = t & 7;
  const int sg = (g0 ^ (r0 & 7)) * 8;
  const bf16* ksrc0 = Kh  + baseQK + (size_t)r0 * 64 + sg;
  const bf16* ksrc1 = Kh  + baseQK + (size_t)(r0 + 32) * 64 + sg;
  const bf16* vsrc0 = VhT + baseV  + (size_t)r0 * 2048 + sg;
  const bf16* vsrc1 = VhT + baseV  + (size_t)(r0 + 32) * 2048 + sg;

  auto stage = [&](int buf, int ti) {
    GLD16(ksrc0 + (size_t)ti * 4096, &Kt[buf][t * 8]);
    GLD16(ksrc1 + (size_t)ti * 4096, &Kt[buf][2048 + t * 8]);
    GLD16(vsrc0 + ti * 64,           &Vt[buf][t * 8]);
    GLD16(vsrc1 + ti * 64,           &Vt[buf][2048 + t * 8]);
  };

  f32x16 o0 = ZV16, o1 = ZV16;
  float m = -1e30f, l = 0.f;
  const int swz = (l31 & 7);

  stage(0, 0);
  for (int ti = 0; ti < 32; ++ti) {
    const int buf = ti & 1;
    __syncthreads();
    if (ti < 31) stage(buf ^ 1, ti + 1);

    f32x16 s0 = ZV16, s1 = ZV16;
    __builtin_amdgcn_s_setprio(1);
#pragma unroll
    for (int kc = 0; kc < 4; ++kc) {
      const int gr = ((kc * 2 + hi) ^ swz) * 8;
      short8 kf0 = *(const short8*)&Kt[buf][l31 * 64 + gr];
      short8 kf1 = *(const short8*)&Kt[buf][(32 + l31) * 64 + gr];
      s0 = mfma32(kf0, qf[kc], s0);
      s1 = mfma32(kf1, qf[kc], s1);
    }
    __builtin_amdgcn_s_setprio(0);

    float tm8[8];
#pragma unroll
    for (int i2 = 0; i2 < 8; ++i2)
      tm8[i2] = fmaxf(fmaxf(s0[i2], s0[i2 + 8]), fmaxf(s1[i2], s1[i2 + 8]));
    float pm = fmaxf(fmaxf(fmaxf(tm8[0], tm8[1]), fmaxf(tm8[2], tm8[3])),
                     fmaxf(fmaxf(tm8[4], tm8[5]), fmaxf(tm8[6], tm8[7])));
    pm = fmaxf(pm, __shfl_xor(pm, 32));
    float mn = fmaxf(m, pm);
    float corr = fexp2((m - mn) * SC2f);
    m = mn;
    float nb = -mn * SC2f;
#pragma unroll
    for (int r = 0; r < 16; ++r) {
      s0[r] = fexp2(s0[r] * SC2f + nb);
      s1[r] = fexp2(s1[r] * SC2f + nb);
    }
    float ts8[8];
#pragma unroll
    for (int i2 = 0; i2 < 8; ++i2)
      ts8[i2] = (s0[i2] + s0[i2 + 8]) + (s1[i2] + s1[i2 + 8]);
    float rs = ((ts8[0] + ts8[1]) + (ts8[2] + ts8[3])) +
               ((ts8[4] + ts8[5]) + (ts8[6] + ts8[7]));
    rs += __shfl_xor(rs, 32);
    l = l * corr + rs;
#pragma unroll
    for (int r = 0; r < 16; ++r) { o0[r] *= corr; o1[r] *= corr; }

    short8 pf[4];
    {
      union U { int i[4]; short8 s8; } fr[4];
      int wds[16];
#pragma unroll
      for (int j = 0; j < 8; ++j) wds[j]     = cvtpk(s0[2 * j], s0[2 * j + 1]);
#pragma unroll
      for (int j = 0; j < 8; ++j) wds[8 + j] = cvtpk(s1[2 * j], s1[2 * j + 1]);
#pragma unroll
      for (int fb = 0; fb < 4; ++fb) {
        int a0 = wds[fb * 4 + 0], a1 = wds[fb * 4 + 1];
        int a2 = wds[fb * 4 + 2], a3 = wds[fb * 4 + 3];
#if __has_builtin(__builtin_amdgcn_permlane32_swap)
        auto s02 = __builtin_amdgcn_permlane32_swap(a0, a2, false, false);
        auto s13 = __builtin_amdgcn_permlane32_swap(a1, a3, false, false);
        fr[fb].i[0] = s02[0]; fr[fb].i[1] = s13[0];
        fr[fb].i[2] = s02[1]; fr[fb].i[3] = s13[1];
#else
        int x0 = __shfl_xor(a0, 32), x2 = __shfl_xor(a2, 32);
        int x1 = __shfl_xor(a1, 32), x3 = __shfl_xor(a3, 32);
        fr[fb].i[0] = hi ? x2 : a0; fr[fb].i[1] = hi ? x3 : a1;
        fr[fb].i[2] = hi ? a2 : x0; fr[fb].i[3] = hi ? a3 : x1;
#endif
        pf[fb] = fr[fb].s8;
      }
    }

    __builtin_amdgcn_s_setprio(1);
#pragma unroll
    for (int kc = 0; kc < 4; ++kc) {
      const int gr = ((kc * 2 + hi) ^ swz) * 8;
      short8 vf0 = *(const short8*)&Vt[buf][l31 * 64 + gr];
      short8 vf1 = *(const short8*)&Vt[buf][(32 + l31) * 64 + gr];
      o0 = mfma32(vf0, pf[kc], o0);
      o1 = mfma32(vf1, pf[kc], o1);
    }
    __builtin_amdgcn_s_setprio(0);
  }

  float rl = 1.0f / l;
  bf16* orow = Oh + baseQK + (size_t)(q0 + l31) * 64;
#pragma unroll
  for (int rq = 0; rq < 4; ++rq) {
    B4 u0, u1;
#pragma unroll
    for (int j = 0; j < 4; ++j) {
      u0.h[j] = __float2bfloat16(o0[rq * 4 + j] * rl);
      u1.h[j] = __float2bfloat16(o1[rq * 4 + j] * rl);
    }
    int dbase = rq * 8 + hi * 4;
    *(int2*)&orow[dbase]      = u0.v;
    *(int2*)&orow[32 + dbase] = u1.v;
  }
}

extern "C" void kernel_launch(void* const* d_in, const int* in_sizes, int n_in,
                              void* d_out, int out_size, void* d_ws, size_t ws_size,
                              hipStream_t stream) {
  const float* q  = (const float*)d_in[0];
  const float* k  = (const float*)d_in[1];
  const float* v  = (const float*)d_in[2];
  const float* Wq = (const float*)d_in[3];
  const float* Wk = (const float*)d_in[4];
  const float* Wv = (const float*)d_in[5];
  const float* Wo = (const float*)d_in[6];
  char* ws = (char*)d_ws;
  const size_t MB = 1u << 20;
  bf16* xb  = (bf16*)(ws);            // 24MB: q,k,v bf16 (dead after proj gemm)
  bf16* WT  = (bf16*)(ws + 24 * MB);  // 8MB: WqT,WkT,WvT,WoT'
  bf16* Qh  = (bf16*)(ws + 32 * MB);  // 8MB
  bf16* Kh  = (bf16*)(ws + 40 * MB);  // 8MB
  bf16* VhT = (bf16*)(ws + 48 * MB);  // 8MB
  bf16* Oh  = (bf16*)(ws);            // 8MB, reuses dead cast region

  cast3_kernel<<<dim3(2048, 3), 256, 0, stream>>>(q, k, v, xb);
  wtrans_kernel<<<dim3(16, 16, 4), 256, 0, stream>>>(Wq, Wk, Wv, Wo, WT);
  gemm2p_kernel<<<dim3(4, 16, 3), 512, 0, stream>>>(xb, WT, Qh, Kh, VhT);
  attn_kernel<<<dim3(16, 32), 256, 0, stream>>>(Qh, Kh, VhT, Oh);
  gemmo_kernel<<<dim3(8, 32), 256, 0, stream>>>(Oh, WT + 3 * (1u << 20),
                                                (float*)d_out);
}